// Round 2
// baseline (553.798 us; speedup 1.0000x reference)
//
#include <hip/hip_runtime.h>
#include <hip/hip_bf16.h>

#define N_EDGES   800000
#define IN_DIM    192
#define BM        128        // edges per tile
#define NT1       12         // 192/16 n-tiles, GEMM1
#define NT2       4          // 64/16 n-tiles, GEMM2
#define KS        6          // 192/32 k-steps
#define XPITCH    200        // bf16 elems per LDS row (192 + 8 pad -> 400B stride)

typedef __attribute__((ext_vector_type(8))) short short8;   // 8 x bf16 operand frag
typedef __attribute__((ext_vector_type(4))) float f32x4;    // accumulator frag

// f32 -> bf16 bits, round-to-nearest-even (finite inputs)
__device__ __forceinline__ ushort f2b(float f) {
    unsigned int u = __float_as_uint(f);
    unsigned int r = (u + 0x7FFFu + ((u >> 16) & 1u)) >> 16;
    return (ushort)r;
}

// Static LDS, 150528 B total (gfx950 allows up to 160 KiB/workgroup):
//   Wl  : W1 frags (4608 entries x 16B) then W2 frags (1536 x 16B) = 98304 B
//   XH  : 128 rows x XPITCH bf16 (X, later reused for H)           = 51200 B
//   idxs: 128 x {row,col} int                                      =  1024 B
__global__ __launch_bounds__(512, 2)
void fused_edge_kernel(const float* __restrict__ nf, const float* __restrict__ ef,
                       const int* __restrict__ ei,
                       const float* __restrict__ W1, const float* __restrict__ b1,
                       const float* __restrict__ gamma, const float* __restrict__ beta,
                       const float* __restrict__ W2, const float* __restrict__ b2,
                       float* __restrict__ out)
{
    __shared__ __align__(16) ushort Wl[49152];
    __shared__ __align__(16) ushort XH[BM * XPITCH];
    __shared__ int idxs[BM * 2];

    const int tid  = threadIdx.x;
    const int w    = tid >> 6;          // wave 0..7
    const int lane = tid & 63;
    const int lrow = lane & 15;         // MFMA row (A) / col (C,D)
    const int lg   = lane >> 4;         // k-group / row-group

    // ---- one-time: pack W1,W2 as bf16 MFMA B-fragments into LDS ----
    // entry (t,s,l): lane l holds B[s*32 + (l>>4)*8 + j][t*16 + (l&15)], j=0..7
    for (int i = tid; i < 6144; i += 512) {
        int l = i & 63, ts = i >> 6;
        const float* Wsrc; int t, s, N;
        if (ts < 72) { t = ts / 6; s = ts - t * 6; Wsrc = W1; N = 192; }
        else { int u2 = ts - 72; t = u2 / 6; s = u2 - t * 6; Wsrc = W2; N = 64; }
        int kb  = s * 32 + (l >> 4) * 8;
        int col = t * 16 + (l & 15);
        const float* p = Wsrc + (size_t)kb * N + col;
        ushort tmp[8];
        #pragma unroll
        for (int j = 0; j < 8; ++j) tmp[j] = f2b(p[j * N]);
        uint4 d;
        d.x = tmp[0] | ((unsigned)tmp[1] << 16);
        d.y = tmp[2] | ((unsigned)tmp[3] << 16);
        d.z = tmp[4] | ((unsigned)tmp[5] << 16);
        d.w = tmp[6] | ((unsigned)tmp[7] << 16);
        *(uint4*)&Wl[(size_t)i * 8] = d;
    }

    // per-lane epilogue params (col = t*16 + lrow)
    float b1v[NT1], gv[NT1], bev[NT1], b2v[NT2];
    #pragma unroll
    for (int t = 0; t < NT1; ++t) {
        int c = t * 16 + lrow;
        b1v[t] = b1[c]; gv[t] = gamma[c]; bev[t] = beta[c];
    }
    #pragma unroll
    for (int t = 0; t < NT2; ++t) b2v[t] = b2[t * 16 + lrow];

    const int ntile = N_EDGES / BM;     // 6250
    for (int tile = blockIdx.x; tile < ntile; tile += gridDim.x) {
        const int e0 = tile * BM;

        __syncthreads();   // previous tile's readers done before we overwrite XH/idxs
        if (tid < 256) {
            int which = tid >> 7, le = tid & 127;
            idxs[le * 2 + which] = ei[which * N_EDGES + e0 + le];
        }
        __syncthreads();

        // ---- gather X tile: [128][192] f32 -> bf16 LDS ----
        #pragma unroll
        for (int j = 0; j < 12; ++j) {
            int fi = j * 512 + tid;          // 0..6143 float4 slots
            int le = fi / 48;
            int c4 = fi - le * 48;
            const float* src;
            if (c4 < 16)      src = nf + (size_t)idxs[le * 2]     * 64 + c4 * 4;
            else if (c4 < 32) src = nf + (size_t)idxs[le * 2 + 1] * 64 + (c4 - 16) * 4;
            else              src = ef + (size_t)(e0 + le)        * 64 + (c4 - 32) * 4;
            float4 v = *(const float4*)src;
            uint2 pk;
            pk.x = f2b(v.x) | ((unsigned)f2b(v.y) << 16);
            pk.y = f2b(v.z) | ((unsigned)f2b(v.w) << 16);
            *(uint2*)&XH[le * XPITCH + c4 * 4] = pk;
        }
        __syncthreads();

        // ---- GEMM1: h[128][192] = X @ W1 ; wave w owns rows w*16..w*16+15 ----
        f32x4 acc[NT1];
        #pragma unroll
        for (int t = 0; t < NT1; ++t) { acc[t][0]=0.f; acc[t][1]=0.f; acc[t][2]=0.f; acc[t][3]=0.f; }
        {
            const ushort* arow = &XH[(w * 16 + lrow) * XPITCH];
            #pragma unroll
            for (int k = 0; k < KS; ++k) {
                short8 a = *(const short8*)(arow + k * 32 + lg * 8);
                #pragma unroll
                for (int t = 0; t < NT1; ++t) {
                    short8 b = *(const short8*)&Wl[((t * KS + k) * 64 + lane) * 8];
                    acc[t] = __builtin_amdgcn_mfma_f32_16x16x32_bf16(a, b, acc[t], 0, 0, 0);
                }
            }
        }

        // ---- +b1, LayerNorm (per row, in-register), relu, bf16 -> H in XH ----
        // C/D layout: col = lane&15, row(in strip) = lg*4 + r
        float mu[4], rs[4];
        #pragma unroll
        for (int r = 0; r < 4; ++r) {
            float s = 0.f, q = 0.f;
            #pragma unroll
            for (int t = 0; t < NT1; ++t) {
                float v = acc[t][r] + b1v[t];
                acc[t][r] = v;
                s += v; q += v * v;
            }
            #pragma unroll
            for (int m = 1; m < 16; m <<= 1) {
                s += __shfl_xor(s, m, 64);
                q += __shfl_xor(q, m, 64);
            }
            float mean = s * (1.f / 192.f);
            float var  = q * (1.f / 192.f) - mean * mean;
            mu[r] = mean;
            rs[r] = rsqrtf(var + 1e-5f);
        }
        #pragma unroll
        for (int t = 0; t < NT1; ++t) {
            #pragma unroll
            for (int r = 0; r < 4; ++r) {
                float v = (acc[t][r] - mu[r]) * rs[r] * gv[t] + bev[t];
                v = fmaxf(v, 0.f);
                // same wave's strip only -> no cross-wave hazard, no barrier needed
                XH[(w * 16 + lg * 4 + r) * XPITCH + t * 16 + lrow] = f2b(v);
            }
        }

        // ---- GEMM2: out[128][64] = H @ W2 ----
        f32x4 acc2[NT2];
        #pragma unroll
        for (int t = 0; t < NT2; ++t) { acc2[t][0]=0.f; acc2[t][1]=0.f; acc2[t][2]=0.f; acc2[t][3]=0.f; }
        {
            const ushort* hrow = &XH[(w * 16 + lrow) * XPITCH];
            #pragma unroll
            for (int k = 0; k < KS; ++k) {
                short8 a = *(const short8*)(hrow + k * 32 + lg * 8);
                #pragma unroll
                for (int t = 0; t < NT2; ++t) {
                    short8 b = *(const short8*)&Wl[(4608 + (t * KS + k) * 64 + lane) * 8];
                    acc2[t] = __builtin_amdgcn_mfma_f32_16x16x32_bf16(a, b, acc2[t], 0, 0, 0);
                }
            }
        }

        // ---- epilogue: + b2 + edge_feats residual (f32), store ----
        #pragma unroll
        for (int t = 0; t < NT2; ++t) {
            #pragma unroll
            for (int r = 0; r < 4; ++r) {
                int le2 = w * 16 + lg * 4 + r;
                size_t off = (size_t)(e0 + le2) * 64 + t * 16 + lrow;
                out[off] = acc2[t][r] + b2v[t] + ef[off];
            }
        }
    }
}

extern "C" void kernel_launch(void* const* d_in, const int* in_sizes, int n_in,
                              void* d_out, int out_size, void* d_ws, size_t ws_size,
                              hipStream_t stream) {
    const float* nf    = (const float*)d_in[0];
    const float* ef    = (const float*)d_in[1];
    const int*   ei    = (const int*)d_in[2];
    const float* W1    = (const float*)d_in[3];
    const float* b1    = (const float*)d_in[4];
    const float* gamma = (const float*)d_in[5];
    const float* beta  = (const float*)d_in[6];
    const float* W2    = (const float*)d_in[7];
    const float* b2    = (const float*)d_in[8];
    float* out = (float*)d_out;

    hipLaunchKernelGGL(fused_edge_kernel, dim3(256), dim3(512), 0, stream,
                       nf, ef, ei, W1, b1, gamma, beta, W2, b2, out);
}